// Round 6
// baseline (661.508 us; speedup 1.0000x reference)
//
#include <hip/hip_runtime.h>
#include <stdint.h>

typedef unsigned short u16;
typedef unsigned int   u32;
typedef __bf16 bf16_t;
typedef __attribute__((ext_vector_type(8))) bf16_t bf16x8;
typedef __attribute__((ext_vector_type(4))) float   f32x4;

#define AS_GLOBAL __attribute__((address_space(1)))
#define AS_LDS    __attribute__((address_space(3)))

__device__ __forceinline__ void glds16(const u16* g, u16* l) {
  __builtin_amdgcn_global_load_lds((const AS_GLOBAL u32*)g, (AS_LDS u32*)l, 16, 0, 0);
}
__device__ __forceinline__ u16 f2bf(float f) {
  union { float f; u32 u; } a; a.f = f;
  return (u16)((a.u + 0x7FFFu + ((a.u >> 16) & 1u)) >> 16);  // RTNE
}
__device__ __forceinline__ float bf2f(u16 s) {
  union { u32 u; float f; } a; a.u = ((u32)s) << 16;
  return a.f;
}
union U16x8 { uint4 u; bf16x8 v; u16 h[8]; };

// ---------------- fp32 -> bf16 elementwise (X) ----------------
__global__ __launch_bounds__(256) void cvt_bf16(const float* __restrict__ X, u16* __restrict__ Y) {
  int i = blockIdx.x * 256 + threadIdx.x;            // n4 = 4194304 exactly
  float4 v = ((const float4*)X)[i];
  ushort4 o; o.x = f2bf(v.x); o.y = f2bf(v.y); o.z = f2bf(v.z); o.w = f2bf(v.w);
  ((ushort4*)Y)[i] = o;
}

// ------------- fp32 (K,N) -> bf16 (N,K) transpose-convert -------------
__global__ __launch_bounds__(256) void cvt_transpose(const float* __restrict__ W, u16* __restrict__ Wt,
                                                     int K, int N) {
  __shared__ float t[64][65];
  const int n0 = blockIdx.x * 64, k0 = blockIdx.y * 64;
  const int tid = threadIdx.x;
  const int cr = tid >> 4, cc = (tid & 15) * 4;
#pragma unroll
  for (int p = 0; p < 4; ++p) {
    int r = p * 16 + cr;
    float4 v = *(const float4*)&W[(size_t)(k0 + r) * N + n0 + cc];
    t[r][cc] = v.x; t[r][cc + 1] = v.y; t[r][cc + 2] = v.z; t[r][cc + 3] = v.w;
  }
  __syncthreads();
#pragma unroll
  for (int p = 0; p < 4; ++p) {
    int rr = p * 16 + cr;  // n-local
    ushort4 o;
    o.x = f2bf(t[cc + 0][rr]); o.y = f2bf(t[cc + 1][rr]);
    o.z = f2bf(t[cc + 2][rr]); o.w = f2bf(t[cc + 3][rr]);
    *(ushort4*)&Wt[(size_t)(n0 + rr) * K + k0 + cc] = o;
  }
}

// ---------------- deep-pipelined bf16 GEMM (4-deep ring) ----------------
// C[M,N] = A[M,K] * Bt[N,K]^T.  BM=256, BN in {192,256}, BK=32.
// 512 threads = 8 waves (2M x 4N). LDS: 4-deep ring of 32KB tiles
// (A 256x32 + B 256x32; BN=192 pads B rows 192..255 with junk, never read).
// Per tile t: vmcnt(8) [tiles t+1,t+2 stay in flight] -> barrier ->
// issue(t+3) -> ds_read -> MFMA. Prefetch distance 3 tiles (~1250 cyc
// compute) covers L3/HBM latency; vmcnt never drains below 8 until tail.
// WAR safety: buf[t&3] overwritten by issue(t+3); its readers (iter t-1)
// finished ds_reads before their MFMAs, hence before iter t's barrier.
__device__ __forceinline__ bf16x8 mfma16(bf16x8 a, bf16x8 b, f32x4& acc);

template <int BN, int WRITE_BF16>
__global__ __launch_bounds__(512, 2) void gemm_dp(const u16* __restrict__ A, const u16* __restrict__ Bt,
                                                  void* __restrict__ C, int N, int K) {
  constexpr int NF = BN / 64;                 // n-frags per wave (3 or 4)
  __shared__ __align__(16) u16 lds[4 * 16384];  // 128 KiB

  const int tid = threadIdx.x;
  const int w = tid >> 6, l = tid & 63;
  const int col = l & 15, quad = l >> 4;
  const int m0 = blockIdx.y * 256, n0 = blockIdx.x * BN;
  const int wm = (w >> 2) * 128;
  const int wn = (w & 3) * (BN / 4);

  f32x4 acc[8][NF];
#pragma unroll
  for (int i = 0; i < 8; ++i)
#pragma unroll
    for (int j = 0; j < NF; ++j) acc[i][j] = f32x4{0.f, 0.f, 0.f, 0.f};

  // 16B-slot XOR swizzle (slot ^= (row>>1)&3), both-sides (rule #21):
  // read-side reduces to per-lane constant sx.
  const int sx = ((quad ^ ((col >> 1) & 3)) << 3);
  const int aoff = (wm + col) * 32 + sx;
  const int boff = (wn + col) * 32 + sx;

  const u16* Ab = A + (size_t)m0 * K;
  const u16* Bb = Bt + (size_t)n0 * K;
  const int NT = K >> 5;

  // stage tile t into ring slot t&3: 4 glds16/thread (2 A sweeps, 2 B sweeps)
  auto issue = [&](int t) {
    u16* dA = &lds[(t & 3) * 16384];
    u16* dB = dA + 8192;
    const int kc = t << 5;
#pragma unroll
    for (int s = 0; s < 2; ++s) {
      int i = s * 512 + tid;
      int row = i >> 2;                       // 0..255
      int slot = (i & 3) ^ ((row >> 1) & 3);  // pre-swizzled source
      glds16(Ab + (size_t)row * K + kc + slot * 8, dA + s * 4096 + w * 512);
      glds16(Bb + (size_t)row * K + kc + slot * 8, dB + s * 4096 + w * 512);
    }
  };

  issue(0); issue(1); issue(2);

  for (int t = 0; t < NT; ++t) {
    const int rem = NT - 1 - t;
    if (rem >= 2)      { asm volatile("s_waitcnt vmcnt(8)" ::: "memory"); }
    else if (rem == 1) { asm volatile("s_waitcnt vmcnt(4)" ::: "memory"); }
    else               { asm volatile("s_waitcnt vmcnt(0)" ::: "memory"); }
    __builtin_amdgcn_s_barrier();
    __builtin_amdgcn_sched_barrier(0);
    if (t + 3 < NT) issue(t + 3);

    const u16* dA = &lds[(t & 3) * 16384];
    const u16* dB = dA + 8192;
    bf16x8 a[8], b[NF];
#pragma unroll
    for (int i = 0; i < 8; ++i) a[i] = *(const bf16x8*)&dA[i * 512 + aoff];
#pragma unroll
    for (int j = 0; j < NF; ++j) b[j] = *(const bf16x8*)&dB[j * 512 + boff];
    __builtin_amdgcn_s_setprio(1);
#pragma unroll
    for (int i = 0; i < 8; ++i)
#pragma unroll
      for (int j = 0; j < NF; ++j)
        acc[i][j] = __builtin_amdgcn_mfma_f32_16x16x32_bf16(a[i], b[j], acc[i][j], 0, 0, 0);
    __builtin_amdgcn_s_setprio(0);
  }

  // epilogue: C row = quad*4+reg, col = lane&15 (m89/m91-verified layout)
  if (WRITE_BF16) {
    u16* Cb = (u16*)C;
#pragma unroll
    for (int i = 0; i < 8; ++i)
#pragma unroll
      for (int r = 0; r < 4; ++r) {
        int m = m0 + wm + i * 16 + quad * 4 + r;
        u16* rp = Cb + (size_t)m * N + n0 + wn + col;
#pragma unroll
        for (int j = 0; j < NF; ++j) rp[j * 16] = f2bf(acc[i][j][r]);
      }
  } else {
    float* Cf = (float*)C;
#pragma unroll
    for (int i = 0; i < 8; ++i)
#pragma unroll
      for (int r = 0; r < 4; ++r) {
        int m = m0 + wm + i * 16 + quad * 4 + r;
        float* rp = Cf + (size_t)m * N + n0 + wn + col;
#pragma unroll
        for (int j = 0; j < NF; ++j) rp[j * 16] = acc[i][j][r];
      }
  }
}

// ---------------- smooth (k,v) + RoPE (q,k), vectorized ----------------
__global__ __launch_bounds__(256) void smooth_rope(const u16* __restrict__ QKV, const int* __restrict__ pos,
                                                   const float* __restrict__ ck, const float* __restrict__ cv,
                                                   u16* __restrict__ Q, u16* __restrict__ Kk, u16* __restrict__ V) {
  const int s = blockIdx.x, b = blockIdx.y, tid = threadIdx.x;
  const size_t base = (size_t)(b * 2048 + s) * 6144;
  const bool hasPrev = (s > 0);
  const float p = (float)pos[b * 2048 + s];
  const float L2F = 0.20762050593046f;  // log2(10000)/64

  // Q: 32 heads x 8 octet-pairs = 256 units, one per thread
  {
    const int h = tid >> 3, oc = tid & 7;
    U16x8 a, c;
    a.u = *(const uint4*)&QKV[base + h * 128 + oc * 8];
    c.u = *(const uint4*)&QKV[base + h * 128 + 64 + oc * 8];
    U16x8 o1, o2;
#pragma unroll
    for (int j = 0; j < 8; ++j) {
      int i = oc * 8 + j;
      float x1 = bf2f(a.h[j]), x2 = bf2f(c.h[j]);
      float ang = p * exp2f(-(float)i * L2F);
      float sn, cs; __sincosf(ang, &sn, &cs);
      o1.h[j] = f2bf(x1 * cs - x2 * sn);
      o2.h[j] = f2bf(x2 * cs + x1 * sn);
    }
    size_t o = ((size_t)(b * 32 + h) * 2048 + s) * 128 + oc * 8;
    *(uint4*)&Q[o] = o1.u;
    *(uint4*)&Q[o + 64] = o2.u;
  }
  if (tid < 64) {
    // K: smooth + rope. 8 kv x 8 octet-pairs = 64 units.
    const int kv = tid >> 3, oc = tid & 7;
    const size_t off = base + 4096 + kv * 128 + oc * 8;
    const float f0 = ck[kv], f1 = ck[8 + kv];
    U16x8 a, c;
    a.u = *(const uint4*)&QKV[off];
    c.u = *(const uint4*)&QKV[off + 64];
    U16x8 pa, pc;
    pa.u = make_uint4(0, 0, 0, 0); pc.u = make_uint4(0, 0, 0, 0);
    if (hasPrev) {
      pa.u = *(const uint4*)&QKV[off - 6144];
      pc.u = *(const uint4*)&QKV[off - 6144 + 64];
    }
    U16x8 o1, o2;
#pragma unroll
    for (int j = 0; j < 8; ++j) {
      int i = oc * 8 + j;
      float x1 = bf2f(a.h[j]) * f1 + bf2f(pa.h[j]) * f0;
      float x2 = bf2f(c.h[j]) * f1 + bf2f(pc.h[j]) * f0;
      float ang = p * exp2f(-(float)i * L2F);
      float sn, cs; __sincosf(ang, &sn, &cs);
      o1.h[j] = f2bf(x1 * cs - x2 * sn);
      o2.h[j] = f2bf(x2 * cs + x1 * sn);
    }
    size_t o = ((size_t)(b * 8 + kv) * 2048 + s) * 128 + oc * 8;
    *(uint4*)&Kk[o] = o1.u;
    *(uint4*)&Kk[o + 64] = o2.u;
  } else if (tid < 192) {
    // V: smooth only. 8 kv x 16 octets = 128 units.
    const int u2 = tid - 64;
    const int kv = u2 >> 4, oc = u2 & 15;
    const size_t off = base + 5120 + kv * 128 + oc * 8;
    const float f0 = cv[kv], f1 = cv[8 + kv];
    U16x8 a; a.u = *(const uint4*)&QKV[off];
    U16x8 pa; pa.u = make_uint4(0, 0, 0, 0);
    if (hasPrev) pa.u = *(const uint4*)&QKV[off - 6144];
    U16x8 o1;
#pragma unroll
    for (int j = 0; j < 8; ++j)
      o1.h[j] = f2bf(bf2f(a.h[j]) * f1 + bf2f(pa.h[j]) * f0);
    *(uint4*)&V[((size_t)(b * 8 + kv) * 2048 + s) * 128 + oc * 8] = o1.u;
  }
}

// ---------------- V (B,KV,S,D) -> Vt (B,KV,D,S) ----------------
__global__ __launch_bounds__(256) void transpose_v(const u16* __restrict__ V, u16* __restrict__ Vt) {
  __shared__ u16 t[64][72];
  const int s0 = blockIdx.x * 64, d0 = blockIdx.y * 64, bkv = blockIdx.z;
  const u16* src = V + (size_t)bkv * 2048 * 128;
  u16* dst = Vt + (size_t)bkv * 128 * 2048;
  const int tid = threadIdx.x;
  for (int e = tid; e < 4096; e += 256) {
    int r = e >> 6, c = e & 63;
    t[r][c] = src[(size_t)(s0 + r) * 128 + d0 + c];
  }
  __syncthreads();
  for (int e = tid; e < 4096; e += 256) {
    int r = e >> 6, c = e & 63;  // r = d-local, c = s-local
    dst[(size_t)(d0 + r) * 2048 + s0 + c] = t[c][r];
  }
}

// ---------------- sliding-window GQA flash attention ----------------
// K/V staged via global_load_lds into DOUBLE-BUFFERED LDS with counted
// vmcnt (GEMM-style). No prefetch registers -> no scratch spill.
// 16B-slot XOR swizzle both-sides (rule #21).
__global__ __launch_bounds__(256) void attn_fwd(const u16* __restrict__ Q, const u16* __restrict__ Kk,
                                                const u16* __restrict__ Vt, u16* __restrict__ O) {
  __shared__ __align__(16) union {
    struct { u16 k[2][8192]; u16 v[2][8192]; u16 p[4][1152]; } s;
    u16 epi[64 * 136];
  } sm;
  const int tid = threadIdx.x, w = tid >> 6, l = tid & 63;
  const int col = l & 15, quad = l >> 4;
  // bijective XCD-chunked swizzle: 2048 blocks = 8 XCDs x 256
  const int orig = blockIdx.x + (blockIdx.y << 5);
  const int wid = (orig & 7) * 256 + (orig >> 3);
  const int q0 = (wid & 31) * 64;
  const int bh = wid >> 5;
  const int b = bh >> 5, h = bh & 31, kv = h >> 2;
  const int qrow = q0 + w * 16 + col;  // this lane's query (softmax col / B-frag n)
  const int qlo = q0 + w * 16;

  bf16x8 qf[4];
  {
    const u16* qp = Q + ((size_t)((b * 32 + h) * 2048 + qrow)) * 128 + quad * 8;
#pragma unroll
    for (int dc = 0; dc < 4; ++dc) { U16x8 u; u.u = *(const uint4*)(qp + dc * 32); qf[dc] = u.v; }
  }
  const u16* Kbase = Kk + (size_t)(b * 8 + kv) * 2048 * 128;
  const u16* Vbase = Vt + (size_t)(b * 8 + kv) * 128 * 2048;

  f32x4 of[8];
#pragma unroll
  for (int i = 0; i < 8; ++i) of[i] = f32x4{0.f, 0.f, 0.f, 0.f};
  float m_i = -3.0e38f, l_i = 0.f;

  const int s_lo = q0 >= 511 ? q0 - 511 : 0;
  const int kt_lo = s_lo >> 6, kt_hi = q0 >> 6;

  // K layout: [64 rows][16 slots of 16B], phys_slot = slot ^ (row & 15)
  // V layout: [128 rows][8 slots of 16B], phys_slot = slot ^ (row & 7)
  auto issue = [&](int c, int k0) {
#pragma unroll
    for (int i = 0; i < 4; ++i) {
      const int base = (i * 4 + w) * 64;
      const int Lk = base + l;
      const int rk_ = Lk >> 4;
      const int sk_ = (Lk & 15) ^ (rk_ & 15);
      glds16(Kbase + (size_t)(k0 + rk_) * 128 + sk_ * 8, &sm.s.k[c][base * 8]);
      const int rv_ = Lk >> 3;
      const int sv_ = (Lk & 7) ^ (rv_ & 7);
      glds16(Vbase + (size_t)rv_ * 2048 + k0 + sv_ * 8, &sm.s.v[c][base * 8]);
    }
  };

  issue(0, kt_lo * 64);
  int cur = 0;

  for (int kt = kt_lo; kt <= kt_hi; ++kt) {
    const int k0 = kt * 64;
    if (kt < kt_hi) {
      issue(cur ^ 1, k0 + 64);
      asm volatile("s_waitcnt vmcnt(8)" ::: "memory");
    } else {
      asm volatile("s_waitcnt vmcnt(0)" ::: "memory");
    }
    __builtin_amdgcn_s_barrier();
    __builtin_amdgcn_sched_barrier(0);
    const u16* lK = sm.s.k[cur];
    const u16* lV = sm.s.v[cur];

    // S^T = K * Q^T  (A = K tile, B^T = Q rows)
    f32x4 st[4];
#pragma unroll
    for (int t = 0; t < 4; ++t) {
      st[t] = f32x4{0.f, 0.f, 0.f, 0.f};
#pragma unroll
      for (int dc = 0; dc < 4; ++dc) {
        bf16x8 a = *(const bf16x8*)&lK[(t * 16 + col) * 128 + (((dc * 4 + quad) ^ col) * 8)];
        st[t] = __builtin_amdgcn_mfma_f32_16x16x32_bf16(a, qf[dc], st[t], 0, 0, 0);
      }
    }
    const bool full = (k0 + 63 <= qlo) && (qlo + 15 - k0 < 512);
    float pmax = -3.0e38f;
#pragma unroll
    for (int t = 0; t < 4; ++t)
#pragma unroll
      for (int r = 0; r < 4; ++r) {
        float v = st[t][r] * 0.08838834764831845f;
        if (!full) {
          int key = k0 + t * 16 + quad * 4 + r;
          if (key > qrow || qrow - key >= 512) v = -1.0e30f;
        }
        st[t][r] = v;
        pmax = fmaxf(pmax, v);
      }
    pmax = fmaxf(pmax, __shfl_xor(pmax, 16, 64));
    pmax = fmaxf(pmax, __shfl_xor(pmax, 32, 64));
    float m_new = fmaxf(m_i, pmax);
    float alpha = __expf(m_i - m_new);
    float rsum = 0.f;
#pragma unroll
    for (int t = 0; t < 4; ++t) {
      u16 pk[4];
#pragma unroll
      for (int r = 0; r < 4; ++r) {
        float e = __expf(st[t][r] - m_new);
        rsum += e;
        pk[r] = f2bf(e);
      }
      u32 lo = (u32)pk[0] | ((u32)pk[1] << 16);
      u32 hi = (u32)pk[2] | ((u32)pk[3] << 16);
      *(uint2*)&sm.s.p[w][col * 72 + t * 16 + quad * 4] = make_uint2(lo, hi);
    }
    rsum += __shfl_xor(rsum, 16, 64);
    rsum += __shfl_xor(rsum, 32, 64);
    l_i = l_i * alpha + rsum;
    m_i = m_new;
#pragma unroll
    for (int i = 0; i < 8; ++i) {
      of[i][0] *= alpha; of[i][1] *= alpha; of[i][2] *= alpha; of[i][3] *= alpha;
    }
    // O^T += V^T * P^T  (A = V^T tile, B^T = P rows [query][key])
#pragma unroll
    for (int c = 0; c < 2; ++c) {
      bf16x8 pb = *(const bf16x8*)&sm.s.p[w][col * 72 + c * 32 + quad * 8];
#pragma unroll
      for (int dt = 0; dt < 8; ++dt) {
        bf16x8 a = *(const bf16x8*)&lV[(dt * 16 + col) * 64 + (((c * 4 + quad) ^ (col & 7)) * 8)];
        of[dt] = __builtin_amdgcn_mfma_f32_16x16x32_bf16(a, pb, of[dt], 0, 0, 0);
      }
    }
    __builtin_amdgcn_s_barrier();   // raw: buf[cur] reads done; no vmcnt drain
    cur ^= 1;
  }
  // epilogue: normalize, transpose O^T -> O via LDS, coalesced store
  float invl = 1.f / l_i;
  __syncthreads();
#pragma unroll
  for (int dt = 0; dt < 8; ++dt) {
    u16 pk[4];
#pragma unroll
    for (int r = 0; r < 4; ++r) pk[r] = f2bf(of[dt][r] * invl);
    u32 lo = (u32)pk[0] | ((u32)pk[1] << 16);
    u32 hi = (u32)pk[2] | ((u32)pk[3] << 16);
    *(uint2*)&sm.epi[(w * 16 + col) * 136 + dt * 16 + quad * 4] = make_uint2(lo, hi);
  }
  __syncthreads();
  // 64 q-rows x 128 d = 8192 u16 = 1024 uint4-chunks of 8 elements each
  for (int e = tid; e < 1024; e += 256) {
    int r = e >> 4, c = e & 15;
    uint4 v = *(const uint4*)&sm.epi[r * 136 + c * 8];
    *(uint4*)(O + ((size_t)(b * 2048 + q0 + r) * 4096 + h * 128 + c * 8)) = v;
  }
}

extern "C" void kernel_launch(void* const* d_in, const int* in_sizes, int n_in,
                              void* d_out, int out_size, void* d_ws, size_t ws_size,
                              hipStream_t stream) {
  const float* hs  = (const float*)d_in[0];
  const int*   pos = (const int*)d_in[1];
  const float* wp  = (const float*)d_in[2];
  const float* wo  = (const float*)d_in[3];
  const float* ck  = (const float*)d_in[4];
  const float* cv  = (const float*)d_in[5];
  float* out = (float*)d_out;
  char* ws = (char*)d_ws;

  u16* Xb   = (u16*)(ws);                  // 33554432 B  (reused as Attn)
  u16* Wt   = (u16*)(ws + 33554432);       // 50331648 B  (Wpack^T, reused as Wo^T)
  u16* QKV  = (u16*)(ws + 83886080);       // 50331648 B
  u16* Qb   = (u16*)(ws + 134217728);      // 33554432 B
  u16* Kb   = (u16*)(ws + 167772160);      //  8388608 B
  u16* Vb   = (u16*)(ws + 176160768);      //  8388608 B
  u16* Vtb  = (u16*)(ws + 184549376);      //  8388608 B  (total 192937984)
  u16* Attn = Xb;
  u16* Wot  = Wt;

  cvt_bf16<<<16384, 256, 0, stream>>>(hs, Xb);
  cvt_transpose<<<dim3(96, 64), 256, 0, stream>>>(wp, Wt, 4096, 6144);
  // QKV proj: M=4096, N=6144, K=4096. BN=192 -> 32x16 = 512 blocks = exactly 2 rounds.
  gemm_dp<192, 1><<<dim3(32, 16), 512, 0, stream>>>(Xb, Wt, (void*)QKV, 6144, 4096);
  smooth_rope<<<dim3(2048, 2), 256, 0, stream>>>(QKV, pos, ck, cv, Qb, Kb, Vb);
  transpose_v<<<dim3(32, 2, 16), 256, 0, stream>>>(Vb, Vtb);
  attn_fwd<<<dim3(32, 64), 256, 0, stream>>>(Qb, Kb, Vtb, Attn);
  cvt_transpose<<<dim3(64, 64), 256, 0, stream>>>(wo, Wot, 4096, 4096);
  // Out proj: M=N=K=4096. BN=256 -> 16x16 = 256 blocks = exactly 1/CU.
  gemm_dp<256, 0><<<dim3(16, 16), 512, 0, stream>>>(Attn, Wot, (void*)out, 4096, 4096);
}

// Round 7
// 647.431 us; speedup vs baseline: 1.0217x; 1.0217x over previous
//
#include <hip/hip_runtime.h>
#include <stdint.h>

typedef unsigned short u16;
typedef unsigned int   u32;
typedef __bf16 bf16_t;
typedef __attribute__((ext_vector_type(8))) bf16_t bf16x8;
typedef __attribute__((ext_vector_type(4))) float   f32x4;

#define AS_GLOBAL __attribute__((address_space(1)))
#define AS_LDS    __attribute__((address_space(3)))

__device__ __forceinline__ void glds16(const u16* g, u16* l) {
  __builtin_amdgcn_global_load_lds((const AS_GLOBAL u32*)g, (AS_LDS u32*)l, 16, 0, 0);
}
__device__ __forceinline__ u16 f2bf(float f) {
  union { float f; u32 u; } a; a.f = f;
  return (u16)((a.u + 0x7FFFu + ((a.u >> 16) & 1u)) >> 16);  // RTNE
}
__device__ __forceinline__ float bf2f(u16 s) {
  union { u32 u; float f; } a; a.u = ((u32)s) << 16;
  return a.f;
}
union U16x8 { uint4 u; bf16x8 v; u16 h[8]; };

// ---------------- fp32 -> bf16 elementwise (X) ----------------
__global__ __launch_bounds__(256) void cvt_bf16(const float* __restrict__ X, u16* __restrict__ Y) {
  int i = blockIdx.x * 256 + threadIdx.x;            // n4 = 4194304 exactly
  float4 v = ((const float4*)X)[i];
  ushort4 o; o.x = f2bf(v.x); o.y = f2bf(v.y); o.z = f2bf(v.z); o.w = f2bf(v.w);
  ((ushort4*)Y)[i] = o;
}

// ------------- fp32 (K,N) -> bf16 (N,K) transpose-convert -------------
__global__ __launch_bounds__(256) void cvt_transpose(const float* __restrict__ W, u16* __restrict__ Wt,
                                                     int K, int N) {
  __shared__ float t[64][65];
  const int n0 = blockIdx.x * 64, k0 = blockIdx.y * 64;
  const int tid = threadIdx.x;
  const int cr = tid >> 4, cc = (tid & 15) * 4;
#pragma unroll
  for (int p = 0; p < 4; ++p) {
    int r = p * 16 + cr;
    float4 v = *(const float4*)&W[(size_t)(k0 + r) * N + n0 + cc];
    t[r][cc] = v.x; t[r][cc + 1] = v.y; t[r][cc + 2] = v.z; t[r][cc + 3] = v.w;
  }
  __syncthreads();
#pragma unroll
  for (int p = 0; p < 4; ++p) {
    int rr = p * 16 + cr;  // n-local
    ushort4 o;
    o.x = f2bf(t[cc + 0][rr]); o.y = f2bf(t[cc + 1][rr]);
    o.z = f2bf(t[cc + 2][rr]); o.w = f2bf(t[cc + 3][rr]);
    *(ushort4*)&Wt[(size_t)(n0 + rr) * K + k0 + cc] = o;
  }
}

// ---------------- deep-pipelined bf16 GEMM (8-phase lockstep) ----------------
// C[M,N] = A[M,K] * Bt[N,K]^T.  BM=256, BN in {192,256}, BK=64.
// 512 threads = 8 waves (2M x 4N). Double-buffered LDS, 16B-slot XOR
// swizzle both-sides (rule #21). Staging order & counted-vmcnt identical
// to the proven r5 gemm8p; NEW (m201 template): per-phase barrier pairs —
// {reads+stage -> barrier -> lgkmcnt(0)+sched_barrier -> setprio(1) ->
// MFMA cluster -> setprio(0) -> barrier} x4 per K-tile, keeping all waves'
// LDS-read windows and MFMA windows aligned (T2 swizzle pays only inside
// this lockstep schedule per the regime-gate evidence).
__device__ __forceinline__ void stage256(const u16* gb, u16* ldst, int K, int kc, int tid, int w) {
#pragma unroll
  for (int s = 0; s < 2; ++s) {
    int t = s * 512 + tid;
    int row = t >> 2;                       // 0..255
    int slot = (t & 3) ^ ((row >> 1) & 3);  // inverse (=same) swizzle on source
    glds16(gb + (size_t)row * K + kc + slot * 8, ldst + s * 4096 + w * 512);
  }
}
template <int BN>
__device__ __forceinline__ void stageB(const u16* gb, u16* ldst, int K, int k0, int tid, int w) {
  constexpr int NB = BN / 64;               // sweeps (3 or 4)
#pragma unroll
  for (int s = 0; s < NB; ++s) {
    int t = s * 512 + tid;
    int rr = t >> 2;                        // 0 .. 2*BN-1
    int kh = rr >= BN ? 1 : 0;
    int row = rr - kh * BN;
    int slot = (t & 3) ^ ((row >> 1) & 3);
    glds16(gb + (size_t)row * K + k0 + kh * 32 + slot * 8, ldst + s * 4096 + w * 512);
  }
}

template <int BN, int WRITE_BF16>
__global__ __launch_bounds__(512, 2) void gemm8p(const u16* __restrict__ A, const u16* __restrict__ Bt,
                                                 void* __restrict__ C, int N, int K) {
  constexpr int NF = BN / 64;        // n-frags per wave (3 or 4)
  constexpr int A_U16 = 2 * 256 * 32;        // 16384 u16 (2 kh blocks)
  constexpr int B_U16 = 2 * BN * 32;
  constexpr int BUF = A_U16 + B_U16;
  __shared__ __align__(16) u16 lds[2 * BUF];

  const int tid = threadIdx.x;
  const int w = tid >> 6, l = tid & 63;
  const int col = l & 15, quad = l >> 4;
  const int m0 = blockIdx.y * 256, n0 = blockIdx.x * BN;
  const int wm = (w >> 2) * 128;
  const int wn = (w & 3) * (BN / 4);

  f32x4 acc[8][NF];
#pragma unroll
  for (int i = 0; i < 8; ++i)
#pragma unroll
    for (int j = 0; j < NF; ++j) acc[i][j] = f32x4{0.f, 0.f, 0.f, 0.f};

  // per-lane constant swizzled slot: row bits (1,2) == col bits (1,2)
  const int sx = ((quad ^ ((col >> 1) & 3)) << 3);
  const int aoff = (wm + col) * 32 + sx;
  const int boff = (wn + col) * 32 + sx;

  const u16* Ab = A + (size_t)m0 * K;
  const u16* Bb = Bt + (size_t)n0 * K;
  const int NT = K >> 6;

  // prologue: tile 0 -> buf 0
  stage256(Ab, &lds[0], K, 0, tid, w);          // A-kh0
  stageB<BN>(Bb, &lds[A_U16], K, 0, tid, w);    // B full
  stage256(Ab, &lds[8192], K, 32, tid, w);      // A-kh1

  for (int t = 0; t < NT; ++t) {
    const int c = t & 1;
    const u16* lA = &lds[c * BUF];
    const u16* lB = &lds[c * BUF + A_U16];
    u16* nA = &lds[(c ^ 1) * BUF];
    u16* nB = &lds[(c ^ 1) * BUF + A_U16];
    const int kn = (t + 1) << 6;
    const bool last = (t == NT - 1);

    bf16x8 a[8], b[NF];
    // ---- P0: kh0, j=0,1
    asm volatile("s_waitcnt vmcnt(2)" ::: "memory");
    __builtin_amdgcn_s_barrier();
    __builtin_amdgcn_sched_barrier(0);
#pragma unroll
    for (int i = 0; i < 8; ++i) a[i] = *(const bf16x8*)&lA[i * 512 + aoff];
    b[0] = *(const bf16x8*)&lB[boff];
    b[1] = *(const bf16x8*)&lB[512 + boff];
    if (!last) stage256(Ab, nA, K, kn, tid, w);
    asm volatile("s_waitcnt lgkmcnt(0)" ::: "memory");
    __builtin_amdgcn_sched_barrier(0);
    __builtin_amdgcn_s_setprio(1);
#pragma unroll
    for (int i = 0; i < 8; ++i) {
      acc[i][0] = __builtin_amdgcn_mfma_f32_16x16x32_bf16(a[i], b[0], acc[i][0], 0, 0, 0);
      acc[i][1] = __builtin_amdgcn_mfma_f32_16x16x32_bf16(a[i], b[1], acc[i][1], 0, 0, 0);
    }
    __builtin_amdgcn_s_setprio(0);
    __builtin_amdgcn_s_barrier();
    // ---- P1: kh0, j=2..NF-1
#pragma unroll
    for (int j = 2; j < NF; ++j) b[j] = *(const bf16x8*)&lB[j * 512 + boff];
    if (!last) stageB<BN>(Bb, nB, K, kn, tid, w);
    __builtin_amdgcn_s_barrier();
    asm volatile("s_waitcnt lgkmcnt(0)" ::: "memory");
    __builtin_amdgcn_sched_barrier(0);
    __builtin_amdgcn_s_setprio(1);
#pragma unroll
    for (int i = 0; i < 8; ++i)
#pragma unroll
      for (int j = 2; j < NF; ++j)
        acc[i][j] = __builtin_amdgcn_mfma_f32_16x16x32_bf16(a[i], b[j], acc[i][j], 0, 0, 0);
    __builtin_amdgcn_s_setprio(0);
    __builtin_amdgcn_s_barrier();
    // ---- P2: kh1, j=0,1
    if (last) { asm volatile("s_waitcnt vmcnt(0)" ::: "memory"); }
    else if (BN == 256) { asm volatile("s_waitcnt vmcnt(6)" ::: "memory"); }
    else { asm volatile("s_waitcnt vmcnt(5)" ::: "memory"); }
    __builtin_amdgcn_s_barrier();
    __builtin_amdgcn_sched_barrier(0);
#pragma unroll
    for (int i = 0; i < 8; ++i) a[i] = *(const bf16x8*)&lA[8192 + i * 512 + aoff];
    b[0] = *(const bf16x8*)&lB[B_U16 / 2 + boff];
    b[1] = *(const bf16x8*)&lB[B_U16 / 2 + 512 + boff];
    if (!last) stage256(Ab, nA + 8192, K, kn + 32, tid, w);
    asm volatile("s_waitcnt lgkmcnt(0)" ::: "memory");
    __builtin_amdgcn_sched_barrier(0);
    __builtin_amdgcn_s_setprio(1);
#pragma unroll
    for (int i = 0; i < 8; ++i) {
      acc[i][0] = __builtin_amdgcn_mfma_f32_16x16x32_bf16(a[i], b[0], acc[i][0], 0, 0, 0);
      acc[i][1] = __builtin_amdgcn_mfma_f32_16x16x32_bf16(a[i], b[1], acc[i][1], 0, 0, 0);
    }
    __builtin_amdgcn_s_setprio(0);
    __builtin_amdgcn_s_barrier();
    // ---- P3: kh1, j=2..NF-1
#pragma unroll
    for (int j = 2; j < NF; ++j) b[j] = *(const bf16x8*)&lB[B_U16 / 2 + j * 512 + boff];
    __builtin_amdgcn_s_barrier();
    asm volatile("s_waitcnt lgkmcnt(0)" ::: "memory");
    __builtin_amdgcn_sched_barrier(0);
    __builtin_amdgcn_s_setprio(1);
#pragma unroll
    for (int i = 0; i < 8; ++i)
#pragma unroll
      for (int j = 2; j < NF; ++j)
        acc[i][j] = __builtin_amdgcn_mfma_f32_16x16x32_bf16(a[i], b[j], acc[i][j], 0, 0, 0);
    __builtin_amdgcn_s_setprio(0);
    // no trailing barrier: next iteration's P0 vmcnt+barrier closes the phase
  }

  // epilogue: C row = quad*4+reg, col = lane&15 (m89/m91-verified layout)
  if (WRITE_BF16) {
    u16* Cb = (u16*)C;
#pragma unroll
    for (int i = 0; i < 8; ++i)
#pragma unroll
      for (int r = 0; r < 4; ++r) {
        int m = m0 + wm + i * 16 + quad * 4 + r;
        u16* rp = Cb + (size_t)m * N + n0 + wn + col;
#pragma unroll
        for (int j = 0; j < NF; ++j) rp[j * 16] = f2bf(acc[i][j][r]);
      }
  } else {
    float* Cf = (float*)C;
#pragma unroll
    for (int i = 0; i < 8; ++i)
#pragma unroll
      for (int r = 0; r < 4; ++r) {
        int m = m0 + wm + i * 16 + quad * 4 + r;
        float* rp = Cf + (size_t)m * N + n0 + wn + col;
#pragma unroll
        for (int j = 0; j < NF; ++j) rp[j * 16] = acc[i][j][r];
      }
  }
}

// ---------------- smooth (k,v) + RoPE (q,k), vectorized ----------------
__global__ __launch_bounds__(256) void smooth_rope(const u16* __restrict__ QKV, const int* __restrict__ pos,
                                                   const float* __restrict__ ck, const float* __restrict__ cv,
                                                   u16* __restrict__ Q, u16* __restrict__ Kk, u16* __restrict__ V) {
  const int s = blockIdx.x, b = blockIdx.y, tid = threadIdx.x;
  const size_t base = (size_t)(b * 2048 + s) * 6144;
  const bool hasPrev = (s > 0);
  const float p = (float)pos[b * 2048 + s];
  const float L2F = 0.20762050593046f;  // log2(10000)/64

  // Q: 32 heads x 8 octet-pairs = 256 units, one per thread
  {
    const int h = tid >> 3, oc = tid & 7;
    U16x8 a, c;
    a.u = *(const uint4*)&QKV[base + h * 128 + oc * 8];
    c.u = *(const uint4*)&QKV[base + h * 128 + 64 + oc * 8];
    U16x8 o1, o2;
#pragma unroll
    for (int j = 0; j < 8; ++j) {
      int i = oc * 8 + j;
      float x1 = bf2f(a.h[j]), x2 = bf2f(c.h[j]);
      float ang = p * exp2f(-(float)i * L2F);
      float sn, cs; __sincosf(ang, &sn, &cs);
      o1.h[j] = f2bf(x1 * cs - x2 * sn);
      o2.h[j] = f2bf(x2 * cs + x1 * sn);
    }
    size_t o = ((size_t)(b * 32 + h) * 2048 + s) * 128 + oc * 8;
    *(uint4*)&Q[o] = o1.u;
    *(uint4*)&Q[o + 64] = o2.u;
  }
  if (tid < 64) {
    // K: smooth + rope. 8 kv x 8 octet-pairs = 64 units.
    const int kv = tid >> 3, oc = tid & 7;
    const size_t off = base + 4096 + kv * 128 + oc * 8;
    const float f0 = ck[kv], f1 = ck[8 + kv];
    U16x8 a, c;
    a.u = *(const uint4*)&QKV[off];
    c.u = *(const uint4*)&QKV[off + 64];
    U16x8 pa, pc;
    pa.u = make_uint4(0, 0, 0, 0); pc.u = make_uint4(0, 0, 0, 0);
    if (hasPrev) {
      pa.u = *(const uint4*)&QKV[off - 6144];
      pc.u = *(const uint4*)&QKV[off - 6144 + 64];
    }
    U16x8 o1, o2;
#pragma unroll
    for (int j = 0; j < 8; ++j) {
      int i = oc * 8 + j;
      float x1 = bf2f(a.h[j]) * f1 + bf2f(pa.h[j]) * f0;
      float x2 = bf2f(c.h[j]) * f1 + bf2f(pc.h[j]) * f0;
      float ang = p * exp2f(-(float)i * L2F);
      float sn, cs; __sincosf(ang, &sn, &cs);
      o1.h[j] = f2bf(x1 * cs - x2 * sn);
      o2.h[j] = f2bf(x2 * cs + x1 * sn);
    }
    size_t o = ((size_t)(b * 8 + kv) * 2048 + s) * 128 + oc * 8;
    *(uint4*)&Kk[o] = o1.u;
    *(uint4*)&Kk[o + 64] = o2.u;
  } else if (tid < 192) {
    // V: smooth only. 8 kv x 16 octets = 128 units.
    const int u2 = tid - 64;
    const int kv = u2 >> 4, oc = u2 & 15;
    const size_t off = base + 5120 + kv * 128 + oc * 8;
    const float f0 = cv[kv], f1 = cv[8 + kv];
    U16x8 a; a.u = *(const uint4*)&QKV[off];
    U16x8 pa; pa.u = make_uint4(0, 0, 0, 0);
    if (hasPrev) pa.u = *(const uint4*)&QKV[off - 6144];
    U16x8 o1;
#pragma unroll
    for (int j = 0; j < 8; ++j)
      o1.h[j] = f2bf(bf2f(a.h[j]) * f1 + bf2f(pa.h[j]) * f0);
    *(uint4*)&V[((size_t)(b * 8 + kv) * 2048 + s) * 128 + oc * 8] = o1.u;
  }
}

// ---------------- V (B,KV,S,D) -> Vt (B,KV,D,S) ----------------
__global__ __launch_bounds__(256) void transpose_v(const u16* __restrict__ V, u16* __restrict__ Vt) {
  __shared__ u16 t[64][72];
  const int s0 = blockIdx.x * 64, d0 = blockIdx.y * 64, bkv = blockIdx.z;
  const u16* src = V + (size_t)bkv * 2048 * 128;
  u16* dst = Vt + (size_t)bkv * 128 * 2048;
  const int tid = threadIdx.x;
  for (int e = tid; e < 4096; e += 256) {
    int r = e >> 6, c = e & 63;
    t[r][c] = src[(size_t)(s0 + r) * 128 + d0 + c];
  }
  __syncthreads();
  for (int e = tid; e < 4096; e += 256) {
    int r = e >> 6, c = e & 63;  // r = d-local, c = s-local
    dst[(size_t)(d0 + r) * 2048 + s0 + c] = t[c][r];
  }
}

// ---------------- sliding-window GQA flash attention ----------------
// K/V staged via global_load_lds into DOUBLE-BUFFERED LDS with counted
// vmcnt (GEMM-style). No prefetch registers -> no scratch spill.
// 16B-slot XOR swizzle both-sides (rule #21).
__global__ __launch_bounds__(256) void attn_fwd(const u16* __restrict__ Q, const u16* __restrict__ Kk,
                                                const u16* __restrict__ Vt, u16* __restrict__ O) {
  __shared__ __align__(16) union {
    struct { u16 k[2][8192]; u16 v[2][8192]; u16 p[4][1152]; } s;
    u16 epi[64 * 136];
  } sm;
  const int tid = threadIdx.x, w = tid >> 6, l = tid & 63;
  const int col = l & 15, quad = l >> 4;
  // bijective XCD-chunked swizzle: 2048 blocks = 8 XCDs x 256
  const int orig = blockIdx.x + (blockIdx.y << 5);
  const int wid = (orig & 7) * 256 + (orig >> 3);
  const int q0 = (wid & 31) * 64;
  const int bh = wid >> 5;
  const int b = bh >> 5, h = bh & 31, kv = h >> 2;
  const int qrow = q0 + w * 16 + col;  // this lane's query (softmax col / B-frag n)
  const int qlo = q0 + w * 16;

  bf16x8 qf[4];
  {
    const u16* qp = Q + ((size_t)((b * 32 + h) * 2048 + qrow)) * 128 + quad * 8;
#pragma unroll
    for (int dc = 0; dc < 4; ++dc) { U16x8 u; u.u = *(const uint4*)(qp + dc * 32); qf[dc] = u.v; }
  }
  const u16* Kbase = Kk + (size_t)(b * 8 + kv) * 2048 * 128;
  const u16* Vbase = Vt + (size_t)(b * 8 + kv) * 128 * 2048;

  f32x4 of[8];
#pragma unroll
  for (int i = 0; i < 8; ++i) of[i] = f32x4{0.f, 0.f, 0.f, 0.f};
  float m_i = -3.0e38f, l_i = 0.f;

  const int s_lo = q0 >= 511 ? q0 - 511 : 0;
  const int kt_lo = s_lo >> 6, kt_hi = q0 >> 6;

  // K layout: [64 rows][16 slots of 16B], phys_slot = slot ^ (row & 15)
  // V layout: [128 rows][8 slots of 16B], phys_slot = slot ^ (row & 7)
  auto issue = [&](int c, int k0) {
#pragma unroll
    for (int i = 0; i < 4; ++i) {
      const int base = (i * 4 + w) * 64;
      const int Lk = base + l;
      const int rk_ = Lk >> 4;
      const int sk_ = (Lk & 15) ^ (rk_ & 15);
      glds16(Kbase + (size_t)(k0 + rk_) * 128 + sk_ * 8, &sm.s.k[c][base * 8]);
      const int rv_ = Lk >> 3;
      const int sv_ = (Lk & 7) ^ (rv_ & 7);
      glds16(Vbase + (size_t)rv_ * 2048 + k0 + sv_ * 8, &sm.s.v[c][base * 8]);
    }
  };

  issue(0, kt_lo * 64);
  int cur = 0;

  for (int kt = kt_lo; kt <= kt_hi; ++kt) {
    const int k0 = kt * 64;
    if (kt < kt_hi) {
      issue(cur ^ 1, k0 + 64);
      asm volatile("s_waitcnt vmcnt(8)" ::: "memory");
    } else {
      asm volatile("s_waitcnt vmcnt(0)" ::: "memory");
    }
    __builtin_amdgcn_s_barrier();
    __builtin_amdgcn_sched_barrier(0);
    const u16* lK = sm.s.k[cur];
    const u16* lV = sm.s.v[cur];

    // S^T = K * Q^T  (A = K tile, B^T = Q rows)
    f32x4 st[4];
#pragma unroll
    for (int t = 0; t < 4; ++t) {
      st[t] = f32x4{0.f, 0.f, 0.f, 0.f};
#pragma unroll
      for (int dc = 0; dc < 4; ++dc) {
        bf16x8 a = *(const bf16x8*)&lK[(t * 16 + col) * 128 + (((dc * 4 + quad) ^ col) * 8)];
        st[t] = __builtin_amdgcn_mfma_f32_16x16x32_bf16(a, qf[dc], st[t], 0, 0, 0);
      }
    }
    const bool full = (k0 + 63 <= qlo) && (qlo + 15 - k0 < 512);
    float pmax = -3.0e38f;
#pragma unroll
    for (int t = 0; t < 4; ++t)
#pragma unroll
      for (int r = 0; r < 4; ++r) {
        float v = st[t][r] * 0.08838834764831845f;
        if (!full) {
          int key = k0 + t * 16 + quad * 4 + r;
          if (key > qrow || qrow - key >= 512) v = -1.0e30f;
        }
        st[t][r] = v;
        pmax = fmaxf(pmax, v);
      }
    pmax = fmaxf(pmax, __shfl_xor(pmax, 16, 64));
    pmax = fmaxf(pmax, __shfl_xor(pmax, 32, 64));
    float m_new = fmaxf(m_i, pmax);
    float alpha = __expf(m_i - m_new);
    float rsum = 0.f;
#pragma unroll
    for (int t = 0; t < 4; ++t) {
      u16 pk[4];
#pragma unroll
      for (int r = 0; r < 4; ++r) {
        float e = __expf(st[t][r] - m_new);
        rsum += e;
        pk[r] = f2bf(e);
      }
      u32 lo = (u32)pk[0] | ((u32)pk[1] << 16);
      u32 hi = (u32)pk[2] | ((u32)pk[3] << 16);
      *(uint2*)&sm.s.p[w][col * 72 + t * 16 + quad * 4] = make_uint2(lo, hi);
    }
    rsum += __shfl_xor(rsum, 16, 64);
    rsum += __shfl_xor(rsum, 32, 64);
    l_i = l_i * alpha + rsum;
    m_i = m_new;
#pragma unroll
    for (int i = 0; i < 8; ++i) {
      of[i][0] *= alpha; of[i][1] *= alpha; of[i][2] *= alpha; of[i][3] *= alpha;
    }
    // O^T += V^T * P^T  (A = V^T tile, B^T = P rows [query][key])
#pragma unroll
    for (int c = 0; c < 2; ++c) {
      bf16x8 pb = *(const bf16x8*)&sm.s.p[w][col * 72 + c * 32 + quad * 8];
#pragma unroll
      for (int dt = 0; dt < 8; ++dt) {
        bf16x8 a = *(const bf16x8*)&lV[(dt * 16 + col) * 64 + (((c * 4 + quad) ^ (col & 7)) * 8)];
        of[dt] = __builtin_amdgcn_mfma_f32_16x16x32_bf16(a, pb, of[dt], 0, 0, 0);
      }
    }
    __builtin_amdgcn_s_barrier();   // raw: buf[cur] reads done; no vmcnt drain
    cur ^= 1;
  }
  // epilogue: normalize, transpose O^T -> O via LDS, coalesced store
  float invl = 1.f / l_i;
  __syncthreads();
#pragma unroll
  for (int dt = 0; dt < 8; ++dt) {
    u16 pk[4];
#pragma unroll
    for (int r = 0; r < 4; ++r) pk[r] = f2bf(of[dt][r] * invl);
    u32 lo = (u32)pk[0] | ((u32)pk[1] << 16);
    u32 hi = (u32)pk[2] | ((u32)pk[3] << 16);
    *(uint2*)&sm.epi[(w * 16 + col) * 136 + dt * 16 + quad * 4] = make_uint2(lo, hi);
  }
  __syncthreads();
  // 64 q-rows x 128 d = 8192 u16 = 1024 uint4-chunks of 8 elements each
  for (int e = tid; e < 1024; e += 256) {
    int r = e >> 4, c = e & 15;
    uint4 v = *(const uint4*)&sm.epi[r * 136 + c * 8];
    *(uint4*)(O + ((size_t)(b * 2048 + q0 + r) * 4096 + h * 128 + c * 8)) = v;
  }
}

extern "C" void kernel_launch(void* const* d_in, const int* in_sizes, int n_in,
                              void* d_out, int out_size, void* d_ws, size_t ws_size,
                              hipStream_t stream) {
  const float* hs  = (const float*)d_in[0];
  const int*   pos = (const int*)d_in[1];
  const float* wp  = (const float*)d_in[2];
  const float* wo  = (const float*)d_in[3];
  const float* ck  = (const float*)d_in[4];
  const float* cv  = (const float*)d_in[5];
  float* out = (float*)d_out;
  char* ws = (char*)d_ws;

  u16* Xb   = (u16*)(ws);                  // 33554432 B  (reused as Attn)
  u16* Wt   = (u16*)(ws + 33554432);       // 50331648 B  (Wpack^T, reused as Wo^T)
  u16* QKV  = (u16*)(ws + 83886080);       // 50331648 B
  u16* Qb   = (u16*)(ws + 134217728);      // 33554432 B
  u16* Kb   = (u16*)(ws + 167772160);      //  8388608 B
  u16* Vb   = (u16*)(ws + 176160768);      //  8388608 B
  u16* Vtb  = (u16*)(ws + 184549376);      //  8388608 B  (total 192937984)
  u16* Attn = Xb;
  u16* Wot  = Wt;

  cvt_bf16<<<16384, 256, 0, stream>>>(hs, Xb);
  cvt_transpose<<<dim3(96, 64), 256, 0, stream>>>(wp, Wt, 4096, 6144);
  // QKV proj: M=4096, N=6144, K=4096. BN=192 -> 32x16 = 512 blocks = exactly 2 rounds.
  gemm8p<192, 1><<<dim3(32, 16), 512, 0, stream>>>(Xb, Wt, (void*)QKV, 6144, 4096);
  smooth_rope<<<dim3(2048, 2), 256, 0, stream>>>(QKV, pos, ck, cv, Qb, Kb, Vb);
  transpose_v<<<dim3(32, 2, 16), 256, 0, stream>>>(Vb, Vtb);
  attn_fwd<<<dim3(32, 64), 256, 0, stream>>>(Qb, Kb, Vtb, Attn);
  cvt_transpose<<<dim3(64, 64), 256, 0, stream>>>(wo, Wot, 4096, 4096);
  // Out proj: M=N=K=4096. BN=256 -> 16x16 = 256 blocks = exactly 1/CU.
  gemm8p<256, 0><<<dim3(16, 16), 512, 0, stream>>>(Attn, Wot, (void*)out, 4096, 4096);
}